// Round 3
// baseline (9723.756 us; speedup 1.0000x reference)
//
#include <hip/hip_runtime.h>

// TrainerRNN: 10-layer GRU (T=2048, IN=384, H=768) + linear head (384).
// ROUND 8: data-as-flag publication. R7's per-row chain was ~4 serial LLC
// trips (drain h-stores -> bump lands -> poll observes -> load h row) plus
// an exposed 1800-cyc fp16-convert shadow => 4.35us/row. This round:
//  - |h| <= 1 always (GRU invariant), so bit pattern 0x7F7F7F7F (memset 0x7F)
//    is an impossible value => consumers poll the h ROW directly (3 sc1
//    loads/thread + __syncthreads_and); the passing iteration already holds
//    the data. Chain: store-lands -> observe. ONE LLC trip + poll quantum.
//  - ring slot re-arm: while computing row t, each producer sentinels its
//    own 32-unit slice of slot (t+1)%RING, drains via s_waitcnt vmcnt(0)
//    (hidden under the hh GEMV), THEN stores row-t data. Per-slice ordering
//    (sentinel lands before my row-t data is visible; consumers poll row t+1
//    only after seeing ALL of row t) makes stale-accept impossible.
//  - back-pressure: per-layer progress counter (layers 1..9, 24 bumps/row,
//    off critical path). l+1 completed row r => consumed layer-l row r.
//    Kill of row t+1-RING at row t needs sum >= 24*(t+3-RING) (1-row spread
//    margin); natural lag 2 => ~11 rows of slack, poll returns instantly.
//    Race check: slot s_{t+1} re-sentineled at row t+16 requires l+1 past
//    row t+2 => its shadow read of row t+1 provably complete.
//  - shadow ih GEMV -> v_dot2_f32_f16 (h staged fp16): 144 dot2 vs
//    288 cvt+288 fma; shadow ~900cyc, hidden in the store-land window.
// w_hh stays fp32 in VGPRs (recurrent path accuracy), w_ih fp16 in LDS,
// 8-lane unit groups, butterfly reduces -- unchanged from R7.

#define T_SEQ 2048
#define H_DIM 768
#define IN0   384
#define G3    2304
#define NLAYER 10
#define BPL   24                      // blocks per layer
#define NBLK  (NLAYER * BPL)          // 240
#define UPB   32                      // units per block
#define NTHR  256                     // 4 waves x 8 unit-groups x 8 lanes
#define NOUT  384
#define CTR_STRIDE 32                 // counters 128 B apart
#define RING  16                      // ring rows per layer
#define WIH_STRIDE 776                // 768 + 8 halves pad
#define SENTU 0x7F7F7F7Fu             // sentinel bit pattern (memset 0x7F)

typedef _Float16 half2_t __attribute__((ext_vector_type(2)));
typedef _Float16 half8_t __attribute__((ext_vector_type(8)));

__device__ __forceinline__ float sigm(float x) { return 1.0f / (1.0f + __expf(-x)); }

__device__ __forceinline__ float ldg_dev(const float* p) {
    return __hip_atomic_load(p, __ATOMIC_RELAXED, __HIP_MEMORY_SCOPE_AGENT);
}
__device__ __forceinline__ void stg_dev(float* p, float v) {
    __hip_atomic_store(p, v, __ATOMIC_RELAXED, __HIP_MEMORY_SCOPE_AGENT);
}

__device__ __forceinline__ float dot8(half8_t h, half8_t w, float acc) {
    union U { half8_t v; unsigned u[4]; };
    U H; H.v = h; U W; W.v = w;
#pragma unroll
    for (int j = 0; j < 4; ++j) {
#if __has_builtin(__builtin_amdgcn_fdot2)
        acc = __builtin_amdgcn_fdot2(__builtin_bit_cast(half2_t, H.u[j]),
                                     __builtin_bit_cast(half2_t, W.u[j]), acc, false);
#else
        half2_t a = __builtin_bit_cast(half2_t, H.u[j]);
        half2_t b = __builtin_bit_cast(half2_t, W.u[j]);
        asm volatile("v_dot2_f32_f16 %0, %1, %2, %0" : "+v"(acc) : "v"(a), "v"(b));
#endif
    }
    return acc;
}

extern "C" __global__ __launch_bounds__(NTHR, 1) void gru_flow(
    const float* __restrict__ x,
    const float* __restrict__ wih0,
    const float* __restrict__ whh0,
    const float* __restrict__ bih0,
    const float* __restrict__ bhh0,
    const float* __restrict__ wihS,
    const float* __restrict__ whhS,
    const float* __restrict__ bihS,
    const float* __restrict__ bhhS,
    float* __restrict__ ring,          // 9 layers x RING x 768 (pre-memset 0x7F)
    float* __restrict__ h9,            // 2048 x 768 (pre-memset 0x7F)
    unsigned int* __restrict__ ctr)    // per-layer progress counters (zeroed)
{
    __shared__ _Float16 wih16[96 * WIH_STRIDE];   // 148,992 B
    __shared__ float    hc[8 * 100];              // critical h(t-1) stage, fp32
    __shared__ _Float16 hsd16[8 * 104];           // shadow h_{l-1}(t+1)/x stage, fp16

    const int tid  = threadIdx.x;
    const int lane = tid & 63;
    const int wv   = tid >> 6;         // 0..3
    const int g    = lane >> 3;        // unit-group in wave, 0..7
    const int p    = lane & 7;         // k-slice position, 0..7
    const int ulocal = wv * 8 + g;     // 0..31
    const int bid  = blockIdx.x;
    const int layer = bid / BPL;
    const int sub   = bid % BPL;
    const int uglob = sub * UPB + ulocal;          // 0..767
    const int Din   = layer ? H_DIM : IN0;

    const float* wihL = layer ? wihS + (size_t)(layer - 1) * G3 * H_DIM : wih0;
    const float* whhL = layer ? whhS + (size_t)(layer - 1) * G3 * H_DIM : whh0;
    const float* bihL = layer ? bihS + (size_t)(layer - 1) * G3 : bih0;
    const float* bhhL = layer ? bhhS + (size_t)(layer - 1) * G3 : bhh0;

    // ---- prologue: w_hh -> VGPRs (lane's 96-k slice of its unit's 3 gate rows) ----
    float4 wr[3][24];
#pragma unroll
    for (int gate = 0; gate < 3; ++gate) {
        const float4* src = (const float4*)(whhL + (size_t)(uglob + gate * H_DIM) * H_DIM + 96 * p);
#pragma unroll
        for (int i = 0; i < 24; ++i) wr[gate][i] = src[i];
    }
    const float bhr  = bhhL[uglob], bhz = bhhL[uglob + H_DIM], bhn  = bhhL[uglob + 2 * H_DIM];
    const float bir  = bihL[uglob], biz = bihL[uglob + H_DIM], bin_ = bihL[uglob + 2 * H_DIM];

    // ---- prologue: w_ih -> LDS fp16 ----
    for (int rr = 0; rr < 24; ++rr) {
        const int r = wv * 24 + rr;            // 0..95
        const int u = r / 3, G = r % 3;
        const float* src = wihL + (size_t)(sub * UPB + u + G * H_DIM) * Din;
        _Float16* dst = wih16 + r * WIH_STRIDE;
        for (int k = lane; k < Din; k += 64) dst[k] = (_Float16)src[k];
    }
    __syncthreads();

    // ---- ih GEMV from hsd16 (fp16 x fp16 -> f32 dot2), 8-lane butterfly ----
    auto ih_gemv = [&](float& gr, float& gz, float& gn) {
        float sr = 0.f, sz = 0.f, sn = 0.f;
        if (layer) {
            const half8_t* h8 = (const half8_t*)(hsd16 + p * 104);
            const half8_t* w0 = (const half8_t*)(wih16 + (ulocal * 3 + 0) * WIH_STRIDE + 96 * p);
            const half8_t* w1 = (const half8_t*)(wih16 + (ulocal * 3 + 1) * WIH_STRIDE + 96 * p);
            const half8_t* w2 = (const half8_t*)(wih16 + (ulocal * 3 + 2) * WIH_STRIDE + 96 * p);
#pragma unroll
            for (int i = 0; i < 12; ++i) {
                const half8_t hv = h8[i];
                sr = dot8(hv, w0[i], sr);
                sz = dot8(hv, w1[i], sz);
                sn = dot8(hv, w2[i], sn);
            }
        } else {
            const half8_t* h8 = (const half8_t*)(hsd16 + p * 56);
            const half8_t* w0 = (const half8_t*)(wih16 + (ulocal * 3 + 0) * WIH_STRIDE + 48 * p);
            const half8_t* w1 = (const half8_t*)(wih16 + (ulocal * 3 + 1) * WIH_STRIDE + 48 * p);
            const half8_t* w2 = (const half8_t*)(wih16 + (ulocal * 3 + 2) * WIH_STRIDE + 48 * p);
#pragma unroll
            for (int i = 0; i < 6; ++i) {
                const half8_t hv = h8[i];
                sr = dot8(hv, w0[i], sr);
                sz = dot8(hv, w1[i], sz);
                sn = dot8(hv, w2[i], sn);
            }
        }
#pragma unroll
        for (int off = 1; off <= 4; off <<= 1) {
            sr += __shfl_xor(sr, off, 64);
            sz += __shfl_xor(sz, off, 64);
            sn += __shfl_xor(sn, off, 64);
        }
        gr = sr + bir; gz = sz + biz; gn = sn + bin_;
    };

    // ---- prologue: gi(0) (data-as-flag poll of l-1 slot 0 / x row 0) ----
    float gi_r, gi_z, gi_n;
    if (layer) {
        const float* sr_ = ring + (size_t)((layer - 1) * RING) * H_DIM;
        float sv0, sv1, sv2;
        for (;;) {
            sv0 = ldg_dev(sr_ + tid);
            sv1 = ldg_dev(sr_ + tid + 256);
            sv2 = ldg_dev(sr_ + tid + 512);
            const int ok = (__float_as_uint(sv0) != SENTU) &
                           (__float_as_uint(sv1) != SENTU) &
                           (__float_as_uint(sv2) != SENTU);
            if (__syncthreads_and(ok)) break;
        }
        hsd16[((tid      ) / 96) * 104 + ((tid      ) % 96)] = (_Float16)sv0;
        hsd16[((tid + 256) / 96) * 104 + ((tid + 256) % 96)] = (_Float16)sv1;
        hsd16[((tid + 512) / 96) * 104 + ((tid + 512) % 96)] = (_Float16)sv2;
    } else {
        for (int k = tid; k < IN0; k += NTHR)
            hsd16[(k / 48) * 56 + (k % 48)] = (_Float16)x[k];
    }
    __syncthreads();
    ih_gemv(gi_r, gi_z, gi_n);

    for (int t = 0; t < T_SEQ; ++t) {
        // ---- own-layer poll (data-as-flag): row t-1; data arrives with the flag ----
        if (t > 0) {
            const float* hr = (layer == NLAYER - 1)
                ? h9 + (size_t)(t - 1) * H_DIM
                : ring + (size_t)(layer * RING + ((t - 1) & (RING - 1))) * H_DIM;
            float cv0, cv1, cv2;
            for (;;) {
                cv0 = ldg_dev(hr + tid);
                cv1 = ldg_dev(hr + tid + 256);
                cv2 = ldg_dev(hr + tid + 512);
                const int ok = (__float_as_uint(cv0) != SENTU) &
                               (__float_as_uint(cv1) != SENTU) &
                               (__float_as_uint(cv2) != SENTU);
                if (__syncthreads_and(ok)) break;
            }
            hc[((tid      ) / 96) * 100 + ((tid      ) % 96)] = cv0;
            hc[((tid + 256) / 96) * 100 + ((tid + 256) % 96)] = cv1;
            hc[((tid + 512) / 96) * 100 + ((tid + 512) % 96)] = cv2;
        }
        __syncthreads();

        // ---- re-arm: sentinel my slice of slot (t+1), back-pressure guarded.
        //      Issued BEFORE the GEMV so its LLC latency hides under compute;
        //      the vmcnt(0) below orders it before my row-t data store. ----
        if (p == 0 && layer != NLAYER - 1 && (t + 1) < T_SEQ) {
            if (t >= RING - 1) {
                const unsigned tgt = 24u * (unsigned)(t + 3 - RING);
                while (__hip_atomic_load(&ctr[(layer + 1) * CTR_STRIDE],
                                         __ATOMIC_RELAXED, __HIP_MEMORY_SCOPE_AGENT) < tgt)
                    __builtin_amdgcn_s_sleep(1);
            }
            stg_dev(&ring[(size_t)(layer * RING + ((t + 1) & (RING - 1))) * H_DIM + uglob],
                    __uint_as_float(SENTU));
        }

        // ---- critical: recurrent GEMV from register weights (fp32) ----
        float ar = 0.f, az = 0.f, an = 0.f;
        if (t > 0) {
            const float4* hs = (const float4*)(hc + p * 100);
#pragma unroll
            for (int i = 0; i < 24; ++i) {
                const float4 h4 = hs[i];
                ar += h4.x * wr[0][i].x + h4.y * wr[0][i].y + h4.z * wr[0][i].z + h4.w * wr[0][i].w;
                az += h4.x * wr[1][i].x + h4.y * wr[1][i].y + h4.z * wr[1][i].z + h4.w * wr[1][i].w;
                an += h4.x * wr[2][i].x + h4.y * wr[2][i].y + h4.z * wr[2][i].z + h4.w * wr[2][i].w;
            }
        }
#pragma unroll
        for (int off = 1; off <= 4; off <<= 1) {
            ar += __shfl_xor(ar, off, 64);
            az += __shfl_xor(az, off, 64);
            an += __shfl_xor(an, off, 64);
        }

        // sentinel (and all loads) drained before the data store is issued
        asm volatile("s_waitcnt vmcnt(0)" ::: "memory");

        if (p == 0) {
            const float hp = (t > 0) ? hc[(uglob / 96) * 100 + (uglob % 96)] : 0.f;
            const float r = sigm(ar + bhr + gi_r);
            const float z = sigm(az + bhz + gi_z);
            const float n = tanhf(gi_n + r * (an + bhn));
            float* orow = (layer == NLAYER - 1)
                ? h9 + (size_t)t * H_DIM
                : ring + (size_t)(layer * RING + (t & (RING - 1))) * H_DIM;
            stg_dev(orow + uglob, (1.f - z) * n + z * hp);
        }

        // ---- progress bump (layers 1..9): "completed row t" for l-1's
        //      back-pressure; off critical path, no drain needed. ----
        if (tid == 0 && layer)
            __hip_atomic_fetch_add(&ctr[layer * CTR_STRIDE], 1u,
                                   __ATOMIC_RELAXED, __HIP_MEMORY_SCOPE_AGENT);

        // ---- shadow: gi(t+1); poll l-1 slot (t+1) (usually instant, lag 2) ----
        if ((t + 1) < T_SEQ) {
            if (layer) {
                const float* sr_ = ring + (size_t)((layer - 1) * RING + ((t + 1) & (RING - 1))) * H_DIM;
                float sv0, sv1, sv2;
                for (;;) {
                    sv0 = ldg_dev(sr_ + tid);
                    sv1 = ldg_dev(sr_ + tid + 256);
                    sv2 = ldg_dev(sr_ + tid + 512);
                    const int ok = (__float_as_uint(sv0) != SENTU) &
                                   (__float_as_uint(sv1) != SENTU) &
                                   (__float_as_uint(sv2) != SENTU);
                    if (__syncthreads_and(ok)) break;
                }
                hsd16[((tid      ) / 96) * 104 + ((tid      ) % 96)] = (_Float16)sv0;
                hsd16[((tid + 256) / 96) * 104 + ((tid + 256) % 96)] = (_Float16)sv1;
                hsd16[((tid + 512) / 96) * 104 + ((tid + 512) % 96)] = (_Float16)sv2;
            } else {
                for (int k = tid; k < IN0; k += NTHR)
                    hsd16[(k / 48) * 56 + (k % 48)] = (_Float16)x[(size_t)(t + 1) * IN0 + k];
            }
            __syncthreads();
            ih_gemv(gi_r, gi_z, gi_n);
        }
    }
}

extern "C" __global__ __launch_bounds__(NOUT, 1) void fc_head(
    const float* __restrict__ h,
    const float* __restrict__ fw,
    const float* __restrict__ fb,
    float* __restrict__ out)
{
    __shared__ float hs[H_DIM];
    const int t = blockIdx.x;
    const float* hr = h + (size_t)t * H_DIM;
    for (int k = threadIdx.x; k < H_DIM; k += NOUT) hs[k] = hr[k];
    __syncthreads();

    const int o = threadIdx.x;
    const float4* wr4 = (const float4*)(fw + (size_t)o * H_DIM);
    const float4* hs4 = (const float4*)hs;
    float acc = fb[o];
#pragma unroll 8
    for (int k = 0; k < H_DIM / 4; ++k) {
        const float4 w = wr4[k], hv = hs4[k];
        acc += w.x * hv.x + w.y * hv.y + w.z * hv.z + w.w * hv.w;
    }
    out[(size_t)t * NOUT + o] = acc;
}

extern "C" void kernel_launch(void* const* d_in, const int* in_sizes, int n_in,
                              void* d_out, int out_size, void* d_ws, size_t ws_size,
                              hipStream_t stream)
{
    const float* x    = (const float*)d_in[0];
    const float* wih0 = (const float*)d_in[1];
    const float* whh0 = (const float*)d_in[2];
    const float* bih0 = (const float*)d_in[3];
    const float* bhh0 = (const float*)d_in[4];
    const float* wihS = (const float*)d_in[5];
    const float* whhS = (const float*)d_in[6];
    const float* bihS = (const float*)d_in[7];
    const float* bhhS = (const float*)d_in[8];
    const float* fcw  = (const float*)d_in[9];
    const float* fcb  = (const float*)d_in[10];

    char* ws = (char*)d_ws;
    unsigned int* ctr = (unsigned int*)ws;                     // 64 KB counter region
    float* ring = (float*)(ws + 65536);                        // 9 x 16 x 768 fp32 = 442,368 B
    float* h9   = (float*)(ws + 65536 + 9 * RING * H_DIM * 4); // 2048 x 768 fp32

    hipMemsetAsync(ctr, 0, 65536, stream);
    hipMemsetAsync(ring, 0x7F, (size_t)9 * RING * H_DIM * 4, stream);   // sentinel fill
    hipMemsetAsync(h9,   0x7F, (size_t)T_SEQ * H_DIM * 4, stream);      // sentinel fill

    hipLaunchKernelGGL(gru_flow, dim3(NBLK), dim3(NTHR), 0, stream,
                       x, wih0, whh0, bih0, bhh0, wihS, whhS, bihS, bhhS,
                       ring, h9, ctr);

    hipLaunchKernelGGL(fc_head, dim3(T_SEQ), dim3(NOUT), 0, stream,
                       h9, fcw, fcb, (float*)d_out);
}

// Round 4
// 7689.291 us; speedup vs baseline: 1.2646x; 1.2646x over previous
//
#include <hip/hip_runtime.h>

// TrainerRNN: 10-layer GRU (T=2048, IN=384, H=768) + linear head (384).
// ROUND 9: tagged dataflow + honest registers + off-path shadow.
// R8's measured 4.66us/row is now modeled within 15%: own-poll (2 LLC
// quanta) + back-pressure LLC load exposed in-order EVERY row (~800cy) +
// shadow poll round trip in the tail (~1000cy) + GEMVs. Also: VGPR_Count
// 204 < 288 proves w_hh NEVER fit in registers (gfx950 VALU addresses only
// 256 arch VGPRs; the 512 budget is VGPR+AGPR) -> 1/3 of w_hh spilled;
// FETCH_SIZE ~340MB/dispatch is spill re-reads, not weights (~140MB once).
// Fixes:
//  - 512 threads/block, 16 lanes/unit: w_hh slice = 3 gates x 48 fp32 =
//    144 VGPRs -> honestly registered, no spill; hh GEMV halves per-thread.
//  - tagged publication: one 8B relaxed-agent atomic {f32 val, u32 tag=t+1}.
//    No sentinel re-arm, no vmcnt(0) ordering, no ring memset hazards;
//    exact tag compare kills stale-accept (future-write impossible: ring
//    overwrite is back-pressure-gated by consumer progress counters, see
//    inline proof).
//  - shadow loads ISSUED at iteration top (overlap hh GEMV), validated +
//    staged + dot2-GEMV'd in the tail. Poll stages into LDS inside the
//    loop: __syncthreads_and doubles as the stage barrier.
//  - back-pressure check amortized: ctr[l+1] prefetched to a register on
//    t%4==3 rows, compared (no load) on t%4==0 rows. Bound: overwrite of
//    slot holding row r-16 during rows [t,t+3] needs l+1 min-progress
//    >= t-14; threshold ctr >= 24*((t-12)/4) with intra-layer spread <=1
//    row gives min-row >= 4K-2 >= t-14; steady-state slack ~3 chunks.
// Numerics identical to R8: fp32 recurrent (hh) path, fp16 w_ih + dot2.

#define T_SEQ 2048
#define H_DIM 768
#define IN0   384
#define G3    2304
#define NLAYER 10
#define BPL   24                      // blocks per layer
#define NBLK  (NLAYER * BPL)          // 240
#define UPB   32                      // units per block
#define NTHR  512                     // 8 waves x 4 units x 16 lanes
#define NOUT  384
#define CTR_STRIDE 32                 // counters 128 B apart
#define RING  16                      // ring rows per layer
#define WIH_STRIDE 776                // 768 + 8 halves pad (1552B rows, 16B aligned)
#define HCS_STRIDE 52                 // 48 + 4 pad floats (208B, 16B aligned)
#define HSD_STRIDE 56                 // 48 + 8 pad halves (112B, 16B aligned)
#define HSD0_STRIDE 32                // layer-0: 24 + 8 halves (64B aligned)

typedef _Float16 half2_t __attribute__((ext_vector_type(2)));
typedef _Float16 half8_t __attribute__((ext_vector_type(8)));
typedef unsigned long long u64;

__device__ __forceinline__ float sigm(float x) { return 1.0f / (1.0f + __expf(-x)); }

__device__ __forceinline__ u64 ld64(const u64* p) {
    return __hip_atomic_load(p, __ATOMIC_RELAXED, __HIP_MEMORY_SCOPE_AGENT);
}
__device__ __forceinline__ void st64(u64* p, u64 v) {
    __hip_atomic_store(p, v, __ATOMIC_RELAXED, __HIP_MEMORY_SCOPE_AGENT);
}
__device__ __forceinline__ unsigned ldctr(const unsigned* p) {
    return __hip_atomic_load(p, __ATOMIC_RELAXED, __HIP_MEMORY_SCOPE_AGENT);
}
__device__ __forceinline__ unsigned tag_of(u64 u) { return (unsigned)(u >> 32); }
__device__ __forceinline__ float    val_of(u64 u) { return __uint_as_float((unsigned)u); }
__device__ __forceinline__ u64      pack(float v, unsigned t) {
    return ((u64)t << 32) | (u64)__float_as_uint(v);
}

__device__ __forceinline__ float dot8(half8_t h, half8_t w, float acc) {
    union U { half8_t v; unsigned u[4]; };
    U H; H.v = h; U W; W.v = w;
#pragma unroll
    for (int j = 0; j < 4; ++j) {
#if __has_builtin(__builtin_amdgcn_fdot2)
        acc = __builtin_amdgcn_fdot2(__builtin_bit_cast(half2_t, H.u[j]),
                                     __builtin_bit_cast(half2_t, W.u[j]), acc, false);
#else
        half2_t a = __builtin_bit_cast(half2_t, H.u[j]);
        half2_t b = __builtin_bit_cast(half2_t, W.u[j]);
        asm volatile("v_dot2_f32_f16 %0, %1, %2, %0" : "+v"(acc) : "v"(a), "v"(b));
#endif
    }
    return acc;
}

extern "C" __global__ __launch_bounds__(NTHR, 1) void gru_flow(
    const float* __restrict__ x,
    const float* __restrict__ wih0,
    const float* __restrict__ whh0,
    const float* __restrict__ bih0,
    const float* __restrict__ bhh0,
    const float* __restrict__ wihS,
    const float* __restrict__ whhS,
    const float* __restrict__ bihS,
    const float* __restrict__ bhhS,
    u64* __restrict__ ring64,          // 10 layers x RING x 768 x {f32,tag} (zeroed)
    float* __restrict__ h9,            // 2048 x 768 (layer 9 output, plain)
    unsigned int* __restrict__ ctr)    // per-layer progress counters (zeroed)
{
    __shared__ _Float16 wih16[96 * WIH_STRIDE];   // 148,992 B
    __shared__ float    hcs[16 * HCS_STRIDE];     //   3,328 B
    __shared__ _Float16 hsd16[16 * HSD_STRIDE];   //   1,792 B

    const int tid  = threadIdx.x;
    const int lane = tid & 63;
    const int wv   = tid >> 6;         // 0..7
    const int p    = lane & 15;        // k-slice position, 0..15
    const int ulocal = wv * 4 + (lane >> 4);       // 0..31
    const int bid  = blockIdx.x;
    const int layer = bid / BPL;
    const int sub   = bid % BPL;
    const int uglob = sub * UPB + ulocal;          // 0..767
    const int Din   = layer ? H_DIM : IN0;

    const float* wihL = layer ? wihS + (size_t)(layer - 1) * G3 * H_DIM : wih0;
    const float* whhL = layer ? whhS + (size_t)(layer - 1) * G3 * H_DIM : whh0;
    const float* bihL = layer ? bihS + (size_t)(layer - 1) * G3 : bih0;
    const float* bhhL = layer ? bhhS + (size_t)(layer - 1) * G3 : bhh0;

    // ---- prologue: w_hh -> VGPRs. 16-lane slice: 3 gates x 12 float4 = 144
    //      VGPRs -- fits the 256 arch-VGPR file with room to spare. ----
    float4 wr[3][12];
#pragma unroll
    for (int gate = 0; gate < 3; ++gate) {
        const float4* src = (const float4*)(whhL + (size_t)(uglob + gate * H_DIM) * H_DIM + 48 * p);
#pragma unroll
        for (int i = 0; i < 12; ++i) wr[gate][i] = src[i];
    }
    const float bhr  = bhhL[uglob], bhz = bhhL[uglob + H_DIM], bhn  = bhhL[uglob + 2 * H_DIM];
    const float bir  = bihL[uglob], biz = bihL[uglob + H_DIM], bin_ = bihL[uglob + 2 * H_DIM];

    // ---- prologue: w_ih -> LDS fp16 (8 waves x 12 rows) ----
    for (int rr = 0; rr < 12; ++rr) {
        const int r = wv * 12 + rr;            // 0..95
        const int u = r / 3, G = r % 3;
        const float* src = wihL + (size_t)(sub * UPB + u + G * H_DIM) * Din;
        _Float16* dst = wih16 + r * WIH_STRIDE;
        for (int k = lane; k < Din; k += 64) dst[k] = (_Float16)src[k];
    }
    __syncthreads();

    // ---- ih GEMV from hsd16 (fp16 x fp16 dot2), 16-lane butterfly ----
    float gi_r = 0.f, gi_z = 0.f, gi_n = 0.f;
    auto ih_gemv = [&]() {
        float sr = 0.f, sz = 0.f, sn = 0.f;
        if (layer) {
            const half8_t* h8 = (const half8_t*)(hsd16 + p * HSD_STRIDE);
            const half8_t* w0 = (const half8_t*)(wih16 + (ulocal * 3 + 0) * WIH_STRIDE + 48 * p);
            const half8_t* w1 = (const half8_t*)(wih16 + (ulocal * 3 + 1) * WIH_STRIDE + 48 * p);
            const half8_t* w2 = (const half8_t*)(wih16 + (ulocal * 3 + 2) * WIH_STRIDE + 48 * p);
#pragma unroll
            for (int i = 0; i < 6; ++i) {
                const half8_t hv = h8[i];
                sr = dot8(hv, w0[i], sr);
                sz = dot8(hv, w1[i], sz);
                sn = dot8(hv, w2[i], sn);
            }
        } else {
            const half8_t* h8 = (const half8_t*)(hsd16 + p * HSD0_STRIDE);
            const half8_t* w0 = (const half8_t*)(wih16 + (ulocal * 3 + 0) * WIH_STRIDE + 24 * p);
            const half8_t* w1 = (const half8_t*)(wih16 + (ulocal * 3 + 1) * WIH_STRIDE + 24 * p);
            const half8_t* w2 = (const half8_t*)(wih16 + (ulocal * 3 + 2) * WIH_STRIDE + 24 * p);
#pragma unroll
            for (int i = 0; i < 3; ++i) {
                const half8_t hv = h8[i];
                sr = dot8(hv, w0[i], sr);
                sz = dot8(hv, w1[i], sz);
                sn = dot8(hv, w2[i], sn);
            }
        }
#pragma unroll
        for (int off = 1; off <= 8; off <<= 1) {
            sr += __shfl_xor(sr, off, 64);
            sz += __shfl_xor(sz, off, 64);
            sn += __shfl_xor(sn, off, 64);
        }
        gi_r = sr + bir; gi_z = sz + biz; gi_n = sn + bin_;
    };

    // ---- prologue: gi(0) ----
    if (layer) {
        const u64* sr_ = ring64 + (size_t)(layer - 1) * RING * H_DIM;
        for (;;) {
            const u64 a = ld64(sr_ + tid);
            int ok = (tag_of(a) == 1u);
            hsd16[(tid / 48) * HSD_STRIDE + tid % 48] = (_Float16)val_of(a);
            if (tid < 256) {
                const u64 b = ld64(sr_ + tid + 512);
                ok &= (tag_of(b) == 1u);
                hsd16[((tid + 512) / 48) * HSD_STRIDE + (tid + 512) % 48] = (_Float16)val_of(b);
            }
            if (__syncthreads_and(ok)) break;
            __builtin_amdgcn_s_sleep(1);
        }
    } else {
        if (tid < IN0) hsd16[(tid / 24) * HSD0_STRIDE + tid % 24] = (_Float16)x[tid];
        __syncthreads();
    }
    ih_gemv();

    unsigned bp = 0;                   // prefetched ctr[layer+1]
    u64 sh0 = 0, sh1 = 0;              // shadow-prefetched {val,tag}
    float xsh = 0.f;                   // layer-0 shadow x value

    for (int t = 0; t < T_SEQ; ++t) {
        // ---- back-pressure (amortized): compare prefetched reg; ~never spins ----
        if (layer != NLAYER - 1 && t >= 16 && (t & 3) == 0) {
            const unsigned tgt = 24u * (unsigned)((t - 12) >> 2);
            while (bp < tgt) {
                __builtin_amdgcn_s_sleep(2);
                bp = ldctr(&ctr[(layer + 1) * CTR_STRIDE]);
            }
        }

        const int tn = t + 1;

        // ---- B: issue shadow loads for row t+1 (latency hides under hh GEMV) ----
        if (tn < T_SEQ) {
            if (layer) {
                const u64* sr_ = ring64 + ((size_t)(layer - 1) * RING + (tn & (RING - 1))) * H_DIM;
                sh0 = ld64(sr_ + tid);
                if (tid < 256) sh1 = ld64(sr_ + tid + 512);
            } else if (tid < IN0) {
                xsh = x[(size_t)tn * IN0 + tid];
            }
        }

        // ---- A: own-layer poll of row t-1 (tag == t); stage inside loop so
        //      the consensus barrier doubles as the stage barrier ----
        if (t > 0) {
            const u64* hr = ring64 + ((size_t)layer * RING + ((t - 1) & (RING - 1))) * H_DIM;
            for (;;) {
                const u64 a = ld64(hr + tid);
                int ok = (tag_of(a) == (unsigned)t);
                hcs[(tid / 48) * HCS_STRIDE + tid % 48] = val_of(a);
                if (tid < 256) {
                    const u64 b = ld64(hr + tid + 512);
                    ok &= (tag_of(b) == (unsigned)t);
                    hcs[((tid + 512) / 48) * HCS_STRIDE + (tid + 512) % 48] = val_of(b);
                }
                if (__syncthreads_and(ok)) break;
            }
        } else {
            __syncthreads();   // order prologue hsd16 reads vs iter-0 tail writes
        }

        // ---- C: recurrent GEMV from registers (fp32), butterfly, gates, store ----
        float ar = 0.f, az = 0.f, an = 0.f;
        if (t > 0) {
            const float4* hs = (const float4*)(hcs + p * HCS_STRIDE);
#pragma unroll
            for (int i = 0; i < 12; ++i) {
                const float4 h4 = hs[i];
                ar += h4.x * wr[0][i].x + h4.y * wr[0][i].y + h4.z * wr[0][i].z + h4.w * wr[0][i].w;
                az += h4.x * wr[1][i].x + h4.y * wr[1][i].y + h4.z * wr[1][i].z + h4.w * wr[1][i].w;
                an += h4.x * wr[2][i].x + h4.y * wr[2][i].y + h4.z * wr[2][i].z + h4.w * wr[2][i].w;
            }
        }
#pragma unroll
        for (int off = 1; off <= 8; off <<= 1) {
            ar += __shfl_xor(ar, off, 64);
            az += __shfl_xor(az, off, 64);
            an += __shfl_xor(an, off, 64);
        }
        if (p == 0) {
            const float hp = (t > 0) ? hcs[(uglob / 48) * HCS_STRIDE + uglob % 48] : 0.f;
            const float r = sigm(ar + bhr + gi_r);
            const float z = sigm(az + bhz + gi_z);
            const float n = tanhf(gi_n + r * (an + bhn));
            const float hnew = (1.f - z) * n + z * hp;
            st64(&ring64[((size_t)layer * RING + (t & (RING - 1))) * H_DIM + uglob],
                 pack(hnew, (unsigned)(t + 1)));
            if (layer == NLAYER - 1) h9[(size_t)t * H_DIM + uglob] = hnew;
        }

        // ---- D: tail -- validate shadow tags (== t+2), stage, dot2 GEMV.
        //      Overwrite-while-in-flight impossible: l-1 may only overwrite
        //      slot (t+1)%RING after observing OUR ctr bump, which happens in
        //      E AFTER this read completes. ----
        if (tn < T_SEQ) {
            if (layer) {
                for (;;) {
                    int ok = (tag_of(sh0) == (unsigned)(tn + 1));
                    hsd16[(tid / 48) * HSD_STRIDE + tid % 48] = (_Float16)val_of(sh0);
                    if (tid < 256) {
                        ok &= (tag_of(sh1) == (unsigned)(tn + 1));
                        hsd16[((tid + 512) / 48) * HSD_STRIDE + (tid + 512) % 48] = (_Float16)val_of(sh1);
                    }
                    if (__syncthreads_and(ok)) break;
                    const u64* sr_ = ring64 + ((size_t)(layer - 1) * RING + (tn & (RING - 1))) * H_DIM;
                    sh0 = ld64(sr_ + tid);
                    if (tid < 256) sh1 = ld64(sr_ + tid + 512);
                }
            } else {
                if (tid < IN0) hsd16[(tid / 24) * HSD0_STRIDE + tid % 24] = (_Float16)xsh;
                __syncthreads();
            }
            ih_gemv();
        }

        // ---- E: progress bump + back-pressure prefetch (every 4 rows) ----
        if ((t & 3) == 3) {
            if (tid == 0 && layer)
                __hip_atomic_fetch_add(&ctr[layer * CTR_STRIDE], 1u,
                                       __ATOMIC_RELAXED, __HIP_MEMORY_SCOPE_AGENT);
            if (layer != NLAYER - 1)
                bp = ldctr(&ctr[(layer + 1) * CTR_STRIDE]);
        }
    }
}

extern "C" __global__ __launch_bounds__(NOUT, 1) void fc_head(
    const float* __restrict__ h,
    const float* __restrict__ fw,
    const float* __restrict__ fb,
    float* __restrict__ out)
{
    __shared__ float hs[H_DIM];
    const int t = blockIdx.x;
    const float* hr = h + (size_t)t * H_DIM;
    for (int k = threadIdx.x; k < H_DIM; k += NOUT) hs[k] = hr[k];
    __syncthreads();

    const int o = threadIdx.x;
    const float4* wr4 = (const float4*)(fw + (size_t)o * H_DIM);
    const float4* hs4 = (const float4*)hs;
    float acc = fb[o];
#pragma unroll 8
    for (int k = 0; k < H_DIM / 4; ++k) {
        const float4 w = wr4[k], hv = hs4[k];
        acc += w.x * hv.x + w.y * hv.y + w.z * hv.z + w.w * hv.w;
    }
    out[(size_t)t * NOUT + o] = acc;
}

extern "C" void kernel_launch(void* const* d_in, const int* in_sizes, int n_in,
                              void* d_out, int out_size, void* d_ws, size_t ws_size,
                              hipStream_t stream)
{
    const float* x    = (const float*)d_in[0];
    const float* wih0 = (const float*)d_in[1];
    const float* whh0 = (const float*)d_in[2];
    const float* bih0 = (const float*)d_in[3];
    const float* bhh0 = (const float*)d_in[4];
    const float* wihS = (const float*)d_in[5];
    const float* whhS = (const float*)d_in[6];
    const float* bihS = (const float*)d_in[7];
    const float* bhhS = (const float*)d_in[8];
    const float* fcw  = (const float*)d_in[9];
    const float* fcb  = (const float*)d_in[10];

    char* ws = (char*)d_ws;
    unsigned int* ctr = (unsigned int*)ws;                 // 64 KB counter region
    u64* ring64 = (u64*)(ws + 65536);                      // 10*16*768*8 = 983,040 B
    float* h9   = (float*)(ws + 65536 + (size_t)NLAYER * RING * H_DIM * 8); // 2048x768 f32

    hipMemsetAsync(ctr, 0, 65536, stream);
    hipMemsetAsync(ring64, 0, (size_t)NLAYER * RING * H_DIM * 8, stream);  // tag 0 = invalid

    hipLaunchKernelGGL(gru_flow, dim3(NBLK), dim3(NTHR), 0, stream,
                       x, wih0, whh0, bih0, bhh0, wihS, whhS, bihS, bhhS,
                       ring64, h9, ctr);

    hipLaunchKernelGGL(fc_head, dim3(T_SEQ), dim3(NOUT), 0, stream,
                       h9, fcw, fcb, (float*)d_out);
}

// Round 5
// 7000.085 us; speedup vs baseline: 1.3891x; 1.0985x over previous
//
#include <hip/hip_runtime.h>

// TrainerRNN: 10-layer GRU (T=2048, IN=384, H=768) + linear head (384).
// ROUND 10: one barrier per row + per-thread spins + pipelined samples.
// R9 measured 3.72us/row (8.9k cy) vs ~2.5-3k cy of actual work+1 LLC trip.
// The gap was barrier-amplified polling: both poll loops ran a full 8-wave
// __syncthreads_and PER ITERATION (~700cy load + ~400cy barrier each), and
// one stale word forced all 512 threads to redo a barrier'd iteration.
// This round:
//  - per-thread spin on each thread's own tagged words (dependent reloads,
//    no barrier in the loop); threads drop out individually.
//  - ONE __syncthreads per row. LDS h-stages are double-buffered by t&1:
//    writes to buf[b] at row t+2 occur after barrier t+1, which post-dates
//    every row-t read of buf[b] -> single barrier is sufficient.
//  - samples issued one row EARLY (right after the h(t) store, before
//    ih_gemv): own h(t) and shadow (l-1,t+2) loads fly under ih_gemv +
//    loop tail (~500+cy), so validation typically sees fresh data already
//    in registers; stale threads re-load individually.
//  - publish path per row: spin(own) -> stage -> barrier -> hh GEMV ->
//    gates -> st64. Everything else (shadow validate, ih GEMV, bumps) sits
//    after the store.
// Tag/back-pressure scheme identical to R9 (relaxed AGENT atomics, 8B
// {f32,tag} words, per-layer progress counters every 4 rows). Sample-early
// safety: own slot t&15 can only hold tags {t-15, t+1} while I'm at row t
// (intra-layer spread <=1); shadow slot (t+2)&15 can only hold
// {t-13, t+3} (overwrite to t+19 requires MY progress past row ~t+6 via
// ctr back-pressure). Spins wait for the exact tag -> stale-accept
// impossible. Numerics identical to R9 (fp32 hh path, fp16 w_ih + dot2).

#define T_SEQ 2048
#define H_DIM 768
#define IN0   384
#define G3    2304
#define NLAYER 10
#define BPL   24                      // blocks per layer
#define NBLK  (NLAYER * BPL)          // 240
#define UPB   32                      // units per block
#define NTHR  512                     // 8 waves x 4 units x 16 lanes
#define NOUT  384
#define CTR_STRIDE 32                 // counters 128 B apart
#define RING  16                      // ring rows per layer
#define WIH_STRIDE 776                // 768 + 8 halves pad (1552B rows)
#define HCS_STRIDE 52                 // 48 + 4 pad floats (208B)
#define HSD_STRIDE 56                 // 48 + 8 pad halves (112B)
#define HSD0_STRIDE 32                // layer-0: 24 + 8 halves (64B)

typedef _Float16 half2_t __attribute__((ext_vector_type(2)));
typedef _Float16 half8_t __attribute__((ext_vector_type(8)));
typedef unsigned long long u64;

__device__ __forceinline__ float sigm(float x) { return 1.0f / (1.0f + __expf(-x)); }

__device__ __forceinline__ u64 ld64(const u64* p) {
    return __hip_atomic_load(p, __ATOMIC_RELAXED, __HIP_MEMORY_SCOPE_AGENT);
}
__device__ __forceinline__ void st64(u64* p, u64 v) {
    __hip_atomic_store(p, v, __ATOMIC_RELAXED, __HIP_MEMORY_SCOPE_AGENT);
}
__device__ __forceinline__ unsigned ldctr(const unsigned* p) {
    return __hip_atomic_load(p, __ATOMIC_RELAXED, __HIP_MEMORY_SCOPE_AGENT);
}
__device__ __forceinline__ unsigned tag_of(u64 u) { return (unsigned)(u >> 32); }
__device__ __forceinline__ float    val_of(u64 u) { return __uint_as_float((unsigned)u); }
__device__ __forceinline__ u64      pack(float v, unsigned t) {
    return ((u64)t << 32) | (u64)__float_as_uint(v);
}

__device__ __forceinline__ float dot8(half8_t h, half8_t w, float acc) {
    union U { half8_t v; unsigned u[4]; };
    U H; H.v = h; U W; W.v = w;
#pragma unroll
    for (int j = 0; j < 4; ++j) {
#if __has_builtin(__builtin_amdgcn_fdot2)
        acc = __builtin_amdgcn_fdot2(__builtin_bit_cast(half2_t, H.u[j]),
                                     __builtin_bit_cast(half2_t, W.u[j]), acc, false);
#else
        half2_t a = __builtin_bit_cast(half2_t, H.u[j]);
        half2_t b = __builtin_bit_cast(half2_t, W.u[j]);
        asm volatile("v_dot2_f32_f16 %0, %1, %2, %0" : "+v"(acc) : "v"(a), "v"(b));
#endif
    }
    return acc;
}

extern "C" __global__ __launch_bounds__(NTHR, 1) void gru_flow(
    const float* __restrict__ x,
    const float* __restrict__ wih0,
    const float* __restrict__ whh0,
    const float* __restrict__ bih0,
    const float* __restrict__ bhh0,
    const float* __restrict__ wihS,
    const float* __restrict__ whhS,
    const float* __restrict__ bihS,
    const float* __restrict__ bhhS,
    u64* __restrict__ ring64,          // 10 layers x RING x 768 x {f32,tag} (zeroed)
    float* __restrict__ h9,            // 2048 x 768 (layer 9 output, plain)
    unsigned int* __restrict__ ctr)    // per-layer progress counters (zeroed)
{
    __shared__ __align__(16) _Float16 wih16[96 * WIH_STRIDE];       // 148,992 B
    __shared__ __align__(16) float    hcs[2][16 * HCS_STRIDE];      //   6,656 B
    __shared__ __align__(16) _Float16 hsd16[2][16 * HSD_STRIDE];    //   3,584 B

    const int tid  = threadIdx.x;
    const int lane = tid & 63;
    const int wv   = tid >> 6;         // 0..7
    const int p    = lane & 15;        // k-slice position, 0..15
    const int ulocal = wv * 4 + (lane >> 4);       // 0..31
    const int bid  = blockIdx.x;
    const int layer = bid / BPL;
    const int sub   = bid % BPL;
    const int uglob = sub * UPB + ulocal;          // 0..767
    const int Din   = layer ? H_DIM : IN0;
    const bool w2   = (tid < 256);     // this thread also owns word tid+512

    const float* wihL = layer ? wihS + (size_t)(layer - 1) * G3 * H_DIM : wih0;
    const float* whhL = layer ? whhS + (size_t)(layer - 1) * G3 * H_DIM : whh0;
    const float* bihL = layer ? bihS + (size_t)(layer - 1) * G3 : bih0;
    const float* bhhL = layer ? bhhS + (size_t)(layer - 1) * G3 : bhh0;

    // ---- prologue: w_hh -> registers (3 gates x 12 float4 per thread) ----
    float4 wr[3][12];
#pragma unroll
    for (int gate = 0; gate < 3; ++gate) {
        const float4* src = (const float4*)(whhL + (size_t)(uglob + gate * H_DIM) * H_DIM + 48 * p);
#pragma unroll
        for (int i = 0; i < 12; ++i) wr[gate][i] = src[i];
    }
    const float bhr  = bhhL[uglob], bhz = bhhL[uglob + H_DIM], bhn  = bhhL[uglob + 2 * H_DIM];
    const float bir  = bihL[uglob], biz = bihL[uglob + H_DIM], bin_ = bihL[uglob + 2 * H_DIM];

    // ---- prologue: w_ih -> LDS fp16 (8 waves x 12 rows) ----
    for (int rr = 0; rr < 12; ++rr) {
        const int r = wv * 12 + rr;            // 0..95
        const int u = r / 3, G = r % 3;
        const float* src = wihL + (size_t)(sub * UPB + u + G * H_DIM) * Din;
        _Float16* dst = wih16 + r * WIH_STRIDE;
        for (int k = lane; k < Din; k += 64) dst[k] = (_Float16)src[k];
    }
    __syncthreads();

    // ---- ih GEMV from hsd16[b] (fp16 dot2), 16-lane butterfly ----
    float gi_r = 0.f, gi_z = 0.f, gi_n = 0.f;
    auto ih_gemv = [&](int b) {
        float sr = 0.f, sz = 0.f, sn = 0.f;
        if (layer) {
            const half8_t* h8 = (const half8_t*)(&hsd16[b][p * HSD_STRIDE]);
            const half8_t* w0 = (const half8_t*)(wih16 + (ulocal * 3 + 0) * WIH_STRIDE + 48 * p);
            const half8_t* w1 = (const half8_t*)(wih16 + (ulocal * 3 + 1) * WIH_STRIDE + 48 * p);
            const half8_t* wn = (const half8_t*)(wih16 + (ulocal * 3 + 2) * WIH_STRIDE + 48 * p);
#pragma unroll
            for (int i = 0; i < 6; ++i) {
                const half8_t hv = h8[i];
                sr = dot8(hv, w0[i], sr);
                sz = dot8(hv, w1[i], sz);
                sn = dot8(hv, wn[i], sn);
            }
        } else {
            const half8_t* h8 = (const half8_t*)(&hsd16[b][p * HSD0_STRIDE]);
            const half8_t* w0 = (const half8_t*)(wih16 + (ulocal * 3 + 0) * WIH_STRIDE + 24 * p);
            const half8_t* w1 = (const half8_t*)(wih16 + (ulocal * 3 + 1) * WIH_STRIDE + 24 * p);
            const half8_t* wn = (const half8_t*)(wih16 + (ulocal * 3 + 2) * WIH_STRIDE + 24 * p);
#pragma unroll
            for (int i = 0; i < 3; ++i) {
                const half8_t hv = h8[i];
                sr = dot8(hv, w0[i], sr);
                sz = dot8(hv, w1[i], sz);
                sn = dot8(hv, wn[i], sn);
            }
        }
#pragma unroll
        for (int off = 1; off <= 8; off <<= 1) {
            sr += __shfl_xor(sr, off, 64);
            sz += __shfl_xor(sz, off, 64);
            sn += __shfl_xor(sn, off, 64);
        }
        gi_r = sr + bir; gi_z = sz + biz; gi_n = sn + bin_;
    };

    // ---- prologue: gi(0) from (l-1,0)/x(0), staged into buf 1 ----
    if (layer) {
        const u64* sp = ring64 + (size_t)(layer - 1) * RING * H_DIM;
        u64 a = ld64(sp + tid);
        while (tag_of(a) != 1u) a = ld64(sp + tid);
        hsd16[1][(tid / 48) * HSD_STRIDE + tid % 48] = (_Float16)val_of(a);
        if (w2) {
            u64 c = ld64(sp + tid + 512);
            while (tag_of(c) != 1u) c = ld64(sp + tid + 512);
            hsd16[1][((tid + 512) / 48) * HSD_STRIDE + (tid + 512) % 48] = (_Float16)val_of(c);
        }
    } else {
        if (tid < IN0) hsd16[1][(tid / 24) * HSD0_STRIDE + tid % 24] = (_Float16)x[tid];
    }
    __syncthreads();
    ih_gemv(1);

    // ---- initial samples for row 0's shadow validate: (l-1,1), tag 2 ----
    u64 ca0 = 0, ca1 = 0, sa0 = 0, sa1 = 0;
    float xs = 0.f;
    if (layer) {
        const u64* sp = ring64 + ((size_t)(layer - 1) * RING + 1) * H_DIM;
        sa0 = ld64(sp + tid);
        if (w2) sa1 = ld64(sp + tid + 512);
    } else if (tid < IN0) {
        xs = x[IN0 + tid];
    }

    unsigned bp = 0;                   // prefetched ctr[layer+1]

    for (int t = 0; t < T_SEQ; ++t) {
        const int b = t & 1;
        const bool have_s = (t + 1) < T_SEQ;

        // ---- back-pressure (amortized, register compare; ~never spins) ----
        if (layer != NLAYER - 1 && t >= 16 && (t & 3) == 0) {
            const unsigned tgt = 24u * (unsigned)((t - 12) >> 2);
            while (bp < tgt) {
                __builtin_amdgcn_s_sleep(2);
                bp = ldctr(&ctr[(layer + 1) * CTR_STRIDE]);
            }
        }

        // ---- 1: validate own h(t-1) (tag t); per-thread spin; stage hcs[b] ----
        if (t > 0) {
            const u64* hr = ring64 + ((size_t)layer * RING + ((t - 1) & (RING - 1))) * H_DIM;
            while (tag_of(ca0) != (unsigned)t) ca0 = ld64(hr + tid);
            hcs[b][(tid / 48) * HCS_STRIDE + tid % 48] = val_of(ca0);
            if (w2) {
                while (tag_of(ca1) != (unsigned)t) ca1 = ld64(hr + tid + 512);
                hcs[b][((tid + 512) / 48) * HCS_STRIDE + (tid + 512) % 48] = val_of(ca1);
            }
        }

        // ---- 2: validate shadow (l-1,t+1) (tag t+2); stage hsd16[b] ----
        if (have_s) {
            if (layer) {
                const u64* sp = ring64 + ((size_t)(layer - 1) * RING + ((t + 1) & (RING - 1))) * H_DIM;
                while (tag_of(sa0) != (unsigned)(t + 2)) sa0 = ld64(sp + tid);
                hsd16[b][(tid / 48) * HSD_STRIDE + tid % 48] = (_Float16)val_of(sa0);
                if (w2) {
                    while (tag_of(sa1) != (unsigned)(t + 2)) sa1 = ld64(sp + tid + 512);
                    hsd16[b][((tid + 512) / 48) * HSD_STRIDE + (tid + 512) % 48] = (_Float16)val_of(sa1);
                }
            } else {
                if (tid < IN0) hsd16[b][(tid / 24) * HSD0_STRIDE + tid % 24] = (_Float16)xs;
            }
        }

        // ---- 3: the row's single barrier ----
        __syncthreads();

        // ---- 4: hh GEMV (fp32 register weights) + butterfly + gates + store ----
        float ar = 0.f, az = 0.f, an = 0.f;
        if (t > 0) {
            const float4* hs = (const float4*)(&hcs[b][p * HCS_STRIDE]);
#pragma unroll
            for (int i = 0; i < 12; ++i) {
                const float4 h4 = hs[i];
                ar += h4.x * wr[0][i].x + h4.y * wr[0][i].y + h4.z * wr[0][i].z + h4.w * wr[0][i].w;
                az += h4.x * wr[1][i].x + h4.y * wr[1][i].y + h4.z * wr[1][i].z + h4.w * wr[1][i].w;
                an += h4.x * wr[2][i].x + h4.y * wr[2][i].y + h4.z * wr[2][i].z + h4.w * wr[2][i].w;
            }
        }
#pragma unroll
        for (int off = 1; off <= 8; off <<= 1) {
            ar += __shfl_xor(ar, off, 64);
            az += __shfl_xor(az, off, 64);
            an += __shfl_xor(an, off, 64);
        }
        if (p == 0) {
            const float hp = (t > 0) ? hcs[b][(uglob / 48) * HCS_STRIDE + uglob % 48] : 0.f;
            const float r = sigm(ar + bhr + gi_r);
            const float z = sigm(az + bhz + gi_z);
            const float n = tanhf(gi_n + r * (an + bhn));
            const float hnew = (1.f - z) * n + z * hp;
            st64(&ring64[((size_t)layer * RING + (t & (RING - 1))) * H_DIM + uglob],
                 pack(hnew, (unsigned)(t + 1)));
            if (layer == NLAYER - 1) h9[(size_t)t * H_DIM + uglob] = hnew;
        }

        // ---- 5: issue next row's samples; they fly under ih_gemv + tail ----
        if (have_s) {
            const u64* hrn = ring64 + ((size_t)layer * RING + (t & (RING - 1))) * H_DIM;
            ca0 = ld64(hrn + tid);
            if (w2) ca1 = ld64(hrn + tid + 512);
            if ((t + 2) < T_SEQ) {
                if (layer) {
                    const u64* spn = ring64 + ((size_t)(layer - 1) * RING + ((t + 2) & (RING - 1))) * H_DIM;
                    sa0 = ld64(spn + tid);
                    if (w2) sa1 = ld64(spn + tid + 512);
                } else if (tid < IN0) {
                    xs = x[(size_t)(t + 2) * IN0 + tid];
                }
            }
        }

        // ---- 6: ih GEMV -> gi(t+1) (reads hsd16[b], behind barrier 3) ----
        if (have_s) ih_gemv(b);

        // ---- 7: progress bump + back-pressure prefetch (every 4 rows) ----
        if ((t & 3) == 3) {
            if (tid == 0 && layer)
                __hip_atomic_fetch_add(&ctr[layer * CTR_STRIDE], 1u,
                                       __ATOMIC_RELAXED, __HIP_MEMORY_SCOPE_AGENT);
            if (layer != NLAYER - 1)
                bp = ldctr(&ctr[(layer + 1) * CTR_STRIDE]);
        }
    }
}

extern "C" __global__ __launch_bounds__(NOUT, 1) void fc_head(
    const float* __restrict__ h,
    const float* __restrict__ fw,
    const float* __restrict__ fb,
    float* __restrict__ out)
{
    __shared__ float hs[H_DIM];
    const int t = blockIdx.x;
    const float* hr = h + (size_t)t * H_DIM;
    for (int k = threadIdx.x; k < H_DIM; k += NOUT) hs[k] = hr[k];
    __syncthreads();

    const int o = threadIdx.x;
    const float4* wr4 = (const float4*)(fw + (size_t)o * H_DIM);
    const float4* hs4 = (const float4*)hs;
    float acc = fb[o];
#pragma unroll 8
    for (int k = 0; k < H_DIM / 4; ++k) {
        const float4 w = wr4[k], hv = hs4[k];
        acc += w.x * hv.x + w.y * hv.y + w.z * hv.z + w.w * hv.w;
    }
    out[(size_t)t * NOUT + o] = acc;
}

extern "C" void kernel_launch(void* const* d_in, const int* in_sizes, int n_in,
                              void* d_out, int out_size, void* d_ws, size_t ws_size,
                              hipStream_t stream)
{
    const float* x    = (const float*)d_in[0];
    const float* wih0 = (const float*)d_in[1];
    const float* whh0 = (const float*)d_in[2];
    const float* bih0 = (const float*)d_in[3];
    const float* bhh0 = (const float*)d_in[4];
    const float* wihS = (const float*)d_in[5];
    const float* whhS = (const float*)d_in[6];
    const float* bihS = (const float*)d_in[7];
    const float* bhhS = (const float*)d_in[8];
    const float* fcw  = (const float*)d_in[9];
    const float* fcb  = (const float*)d_in[10];

    char* ws = (char*)d_ws;
    unsigned int* ctr = (unsigned int*)ws;                 // 64 KB counter region
    u64* ring64 = (u64*)(ws + 65536);                      // 10*16*768*8 = 983,040 B
    float* h9   = (float*)(ws + 65536 + (size_t)NLAYER * RING * H_DIM * 8); // 2048x768 f32

    hipMemsetAsync(ctr, 0, 65536, stream);
    hipMemsetAsync(ring64, 0, (size_t)NLAYER * RING * H_DIM * 8, stream);  // tag 0 = invalid

    hipLaunchKernelGGL(gru_flow, dim3(NBLK), dim3(NTHR), 0, stream,
                       x, wih0, whh0, bih0, bhh0, wihS, whhS, bihS, bhhS,
                       ring64, h9, ctr);

    hipLaunchKernelGGL(fc_head, dim3(T_SEQ), dim3(NOUT), 0, stream,
                       h9, fcw, fcb, (float*)d_out);
}